// Round 22
// baseline (414.394 us; speedup 1.0000x reference)
//
#include <hip/hip_runtime.h>

// GraphNet forward. Round 22: fuse bucketsort INTO escatter. The per-node
// counting sort runs in LDS on the bucket's tmp segment (staged
// sequentially, chunked at CAP for correctness at any bucket size);
// deletes the bucketsort launch + the 51MB srt write/read round trip.
// Sort work absorbs into escatter's idle issue slots (VALU 39%, mem 33%).
// cnt accumulated from per-chunk hist (cnt now in zeroed region).

typedef unsigned int uint;
typedef unsigned short ushort;
typedef __attribute__((ext_vector_type(8))) short bf16x8;
typedef __attribute__((ext_vector_type(4))) float f32x4;

#define BW 128          // nodes per bucket (sort)
#define BSHIFT 7
#define NBMAX 784       // max buckets (N=100000 -> 782)
#define DC 4096         // edges per distribute block (uint2 staging)
#define CAP 1536        // edges per escatter sort chunk (LDS staging)
#define EMASK 0x1FFFFFu // 21 bits of edge id

#define LDF4(p) (*reinterpret_cast<const float4*>(p))

__device__ __forceinline__ ushort f2bf(float f) {
  uint u = __float_as_uint(f);
  u += 0x7FFFu + ((u >> 16) & 1u);
  return (ushort)(u >> 16);
}

// swizzled ushort index of 16B chunk (row, kb) in [row][64] bf16 tile
__device__ __forceinline__ int aswz(int row, int kb) {
  return row * 64 + ((kb ^ (row & 7)) << 3);
}
// [row][128] tile (kb 0..15)
__device__ __forceinline__ int nswz(int row, int kb) {
  return row * 128 + (((kb & 8) | ((kb ^ row) & 7)) << 3);
}
// [row][192] tile (kb 0..23)
__device__ __forceinline__ int aswz192(int row, int kb) {
  return row * 192 + (((kb & 24) | ((kb ^ row) & 7)) << 3);
}

// ---- merged init: weights (block 0) + x->bf16 (blocks 1..nxb) +
//      bucket histogram (last 64 blocks)
__global__ __launch_bounds__(256) void init_kernel(
    const float* __restrict__ x, ushort* __restrict__ xb, int n16, int nxb,
    const int* __restrict__ receivers, const int* __restrict__ senders,
    uint* __restrict__ bcnt_r, uint* __restrict__ bcnt_s, int E, int NB,
    const float* __restrict__ u, const float* __restrict__ W_eb,
    const float* __restrict__ b_eb, const float* __restrict__ W_nb,
    const float* __restrict__ b_nb, const float* __restrict__ W_d1,
    const float* __restrict__ W_d2, float* __restrict__ eb_init,
    float* __restrict__ nb_init, ushort* __restrict__ wt_lin,
    ushort* __restrict__ wnb_img, ushort* __restrict__ wtd1_img,
    ushort* __restrict__ w2_img) {
  if (blockIdx.x == 0) {
    int j = threadIdx.x;
    if (j >= 64) return;
    float ae = b_eb[j], an = b_nb[j];
    for (int k = 0; k < 64; ++k) {
      float uk = u[k];
      ae = fmaf(uk, W_eb[(48 + k) * 64 + j], ae);
      an = fmaf(uk, W_nb[(80 + k) * 64 + j], an);
    }
    eb_init[j] = ae;
    nb_init[j] = an;
    for (int k = 0; k < 64; ++k)
      wt_lin[j * 64 + k] = (k < 48) ? f2bf(W_eb[k * 64 + j]) : (ushort)0;
    for (int k = 0; k < 128; ++k) {
      ushort v = (k < 80) ? f2bf(W_nb[k * 64 + j]) : (ushort)0;
      wnb_img[nswz(j, k >> 3) + (k & 7)] = v;
    }
    for (int k = 0; k < 192; ++k)
      wtd1_img[aswz192(j, k >> 3) + (k & 7)] = f2bf(W_d1[k * 64 + j]);
    if (j < 16)
      for (int k = 0; k < 64; ++k)
        w2_img[aswz(j, k >> 3) + (k & 7)] = f2bf(W_d2[k * 16 + j]);
    return;
  }
  if (blockIdx.x <= nxb) {
    int i = (blockIdx.x - 1) * 256 + threadIdx.x;
    if (i * 4 >= n16) return;
    float4 a = LDF4(x + i * 4);
    ushort4 o = {f2bf(a.x), f2bf(a.y), f2bf(a.z), f2bf(a.w)};
    *reinterpret_cast<ushort4*>(xb + i * 4) = o;
    return;
  }
  // bucket histogram (64 blocks)
  __shared__ uint hr[NBMAX], hs[NBMAX];
  int t = threadIdx.x;
  int bid = blockIdx.x - 1 - nxb;
  for (int i = t; i < NB; i += 256) { hr[i] = 0; hs[i] = 0; }
  __syncthreads();
  int stride = 64 * 256;
  for (int e = bid * 256 + t; e < E; e += stride) {
    atomicAdd(&hr[receivers[e] >> BSHIFT], 1u);
    atomicAdd(&hs[senders[e] >> BSHIFT], 1u);
  }
  __syncthreads();
  for (int i = t; i < NB; i += 256) {
    if (hr[i]) atomicAdd(&bcnt_r[i], hr[i]);
    if (hs[i]) atomicAdd(&bcnt_s[i], hs[i]);
  }
}

// ---- exclusive scan of both bucket-count arrays (single block, 4/thread)
__global__ __launch_bounds__(256) void bscan_kernel(
    const uint* __restrict__ bcnt_r, const uint* __restrict__ bcnt_s,
    uint* __restrict__ start_r, uint* __restrict__ start_s,
    uint* __restrict__ cur_r, uint* __restrict__ cur_s, int E, int NB) {
  __shared__ uint ts[256];
  int t = threadIdx.x;
  #pragma unroll
  for (int pass = 0; pass < 2; ++pass) {
    const uint* cnt = pass ? bcnt_s : bcnt_r;
    uint* start = pass ? start_s : start_r;
    uint* cur = pass ? cur_s : cur_r;
    uint loc[4]; uint tsum = 0;
    #pragma unroll
    for (int q = 0; q < 4; ++q) {
      int i = t * 4 + q;
      loc[q] = (i < NB) ? cnt[i] : 0;
      tsum += loc[q];
    }
    ts[t] = tsum;
    __syncthreads();
    for (int off = 1; off < 256; off <<= 1) {
      uint a = (t >= off) ? ts[t - off] : 0;
      __syncthreads();
      ts[t] += a;
      __syncthreads();
    }
    uint run = ts[t] - tsum;
    #pragma unroll
    for (int q = 0; q < 4; ++q) {
      int i = t * 4 + q;
      if (i < NB) { start[i] = run; cur[i] = run; run += loc[q]; }
    }
    if (t == 0) start[NB] = (uint)E;
    __syncthreads();
  }
}

// ---- bucket-sort, both directions; entry = {(nl<<21)|edge, other_node}
__global__ __launch_bounds__(256) void distribute_kernel(
    const int* __restrict__ receivers, const int* __restrict__ senders,
    uint* __restrict__ gcur_r, uint* __restrict__ gcur_s,
    uint2* __restrict__ tmp_r, uint2* __restrict__ tmp_s, int E, int NB) {
  __shared__ uint hist[NBMAX], lstart[NBMAX], cur[NBMAX], gbase[NBMAX];
  __shared__ uint2 ids[DC];           // 32 KB
  __shared__ ushort idsB[DC];         // 8 KB
  __shared__ uint ts[256];
  int dir = blockIdx.x & 1;
  const int* key = dir ? senders : receivers;
  const int* oth = dir ? receivers : senders;
  uint* g_cursor = dir ? gcur_s : gcur_r;
  uint2* tmp = dir ? tmp_s : tmp_r;
  int t = threadIdx.x;
  int base = (blockIdx.x >> 1) * DC;
  int cact = min(DC, E - base);
  for (int i = t; i < NB; i += 256) hist[i] = 0;
  __syncthreads();
  for (int k = 0; k < DC / 256; ++k) {
    int j = k * 256 + t;
    if (j < cact) atomicAdd(&hist[key[base + j] >> BSHIFT], 1u);
  }
  __syncthreads();
  {
    uint loc[4]; uint tsum = 0;
    #pragma unroll
    for (int q = 0; q < 4; ++q) {
      int i = t * 4 + q;
      loc[q] = (i < NB) ? hist[i] : 0;
      tsum += loc[q];
    }
    ts[t] = tsum;
    __syncthreads();
    for (int off = 1; off < 256; off <<= 1) {
      uint a = (t >= off) ? ts[t - off] : 0;
      __syncthreads();
      ts[t] += a;
      __syncthreads();
    }
    uint run = ts[t] - tsum;
    #pragma unroll
    for (int q = 0; q < 4; ++q) {
      int i = t * 4 + q;
      if (i < NB) { lstart[i] = run; cur[i] = run; run += loc[q]; }
    }
  }
  __syncthreads();
  for (int i = t; i < NB; i += 256)
    if (hist[i]) gbase[i] = atomicAdd(&g_cursor[i], hist[i]);
  for (int k = 0; k < DC / 256; ++k) {
    int j = k * 256 + t;
    if (j < cact) {
      int e = base + j;
      int kk = key[e];
      uint b = (uint)(kk >> BSHIFT);
      uint slot = atomicAdd(&cur[b], 1u);
      ids[slot] = uint2{((uint)(kk & (BW - 1)) << 21) | (uint)e,
                        (uint)oth[e]};
      idsB[slot] = (ushort)b;
    }
  }
  __syncthreads();
  for (int j = t; j < cact; j += 256) {
    uint b2 = idsB[j];
    tmp[gbase[b2] + ((uint)j - lstart[b2])] = ids[j];
  }
}

// ---- FUSED sort + edge-MLP + aggregation. Block = (bucket, dir).
// Stages the bucket's tmp segment in LDS (chunks of CAP), counting-sorts
// to per-node order in LDS (ord), then 4 waves process 16-edge tiles with
// the proven MFMA + segmented-sum path (2-deep attr pipeline per chunk).
__global__ __launch_bounds__(256, 4) void escatter_kernel(
    const float* __restrict__ edge_attr, const ushort* __restrict__ xb,
    const uint2* __restrict__ tmp_r, const uint2* __restrict__ tmp_s,
    const uint* __restrict__ start_r, const uint* __restrict__ start_s,
    const ushort* __restrict__ wt_lin, const float* __restrict__ eb_init,
    float* __restrict__ sum_recv, float* __restrict__ sum_sent,
    uint* __restrict__ cnt_r, uint* __restrict__ cnt_s, int E, int N) {
  __shared__ uint2 stage[CAP];        // 12 KB
  __shared__ ushort ord[CAP];         // 3 KB
  __shared__ uint hist[BW], pfx[BW], cur[BW];
  __shared__ float Clds[4][16 * 72];  // 18 KB, wave-local
  __shared__ int nodeW[4][16];
  int t = threadIdx.x;
  int wid = t >> 6, l = t & 63;
  int lrow = l & 15, lk = l >> 4;
  bf16x8 b0[4], b1[4];
  float ebi[4];
  #pragma unroll
  for (int nt = 0; nt < 4; ++nt) {
    const ushort* wr = wt_lin + (nt * 16 + lrow) * 64;
    b0[nt] = *reinterpret_cast<const bf16x8*>(wr + lk * 8);
    b1[nt] = *reinterpret_cast<const bf16x8*>(wr + 32 + lk * 8);
    ebi[nt] = eb_init[nt * 16 + lrow];
  }
  const bf16x8 zero8 = {0, 0, 0, 0, 0, 0, 0, 0};
  int dir = blockIdx.x & 1;
  int b = blockIdx.x >> 1;
  const uint2* tmp = dir ? tmp_s : tmp_r;
  const uint* start = dir ? start_s : start_r;
  float* sum = dir ? sum_sent : sum_recv;
  uint* cnt = dir ? cnt_s : cnt_r;
  int beg = (int)start[b], end = (int)start[b + 1];
  int nbase = b * BW;

  for (int cbeg = beg; cbeg < end; cbeg += CAP) {
    int cc = min(CAP, end - cbeg);
    // ---- stage + hist (one pass)
    if (t < BW) hist[t] = 0;
    __syncthreads();
    for (int i = t; i < cc; i += 256) {
      uint2 v = tmp[cbeg + i];
      stage[i] = v;
      atomicAdd(&hist[v.x >> 21], 1u);
    }
    __syncthreads();
    // accumulate per-node degree
    if (t < BW && hist[t] && nbase + t < N) atomicAdd(&cnt[nbase + t], hist[t]);
    // ---- prefix scan over 128 node slots
    if (t < BW) pfx[t] = hist[t];
    __syncthreads();
    for (int off = 1; off < BW; off <<= 1) {
      uint a = 0;
      if (t < BW && t >= off) a = pfx[t - off];
      __syncthreads();
      if (t < BW) pfx[t] += a;
      __syncthreads();
    }
    if (t < BW) cur[t] = pfx[t] - hist[t];
    __syncthreads();
    // ---- scatter sorted order (indices only)
    for (int i = t; i < cc; i += 256) {
      uint nl = stage[i].x >> 21;
      uint p = atomicAdd(&cur[nl], 1u);
      ord[p] = (ushort)i;
    }
    __syncthreads();
    // ---- process tiles (4 waves, 2-deep attr pipeline)
    int ntile = (cc + 15) >> 4;
    uint2 vC = {0, 0}, vN = {0, 0};
    bf16x8 a0C = zero8, a1C = zero8;
    if (wid < ntile) {
      int j = min(wid * 16 + lrow, cc - 1);
      vC = stage[ord[j]];
      int e = (int)(vC.x & EMASK);
      int kn = nbase + (int)(vC.x >> 21);
      int on = (int)vC.y;
      int s = dir ? kn : on;
      int r = dir ? on : kn;
      if (lk < 2) {
        const float* ap = edge_attr + (size_t)e * 16 + lk * 8;
        float4 f0 = LDF4(ap), f1 = LDF4(ap + 4);
        union { ushort h[8]; bf16x8 v; } pk;
        pk.h[0] = f2bf(f0.x); pk.h[1] = f2bf(f0.y);
        pk.h[2] = f2bf(f0.z); pk.h[3] = f2bf(f0.w);
        pk.h[4] = f2bf(f1.x); pk.h[5] = f2bf(f1.y);
        pk.h[6] = f2bf(f1.z); pk.h[7] = f2bf(f1.w);
        a0C = pk.v;
        a1C = *reinterpret_cast<const bf16x8*>(xb + (size_t)s * 16 + lk * 8);
      } else {
        a0C = *reinterpret_cast<const bf16x8*>(xb + (size_t)r * 16 +
                                               (lk - 2) * 8);
      }
    }
    for (int wt = wid; wt < ntile; wt += 4) {
      int wtN = wt + 4;
      bf16x8 a0N = zero8, a1N = zero8;
      if (wtN < ntile) {
        int j = min(wtN * 16 + lrow, cc - 1);
        vN = stage[ord[j]];
        int e = (int)(vN.x & EMASK);
        int kn = nbase + (int)(vN.x >> 21);
        int on = (int)vN.y;
        int s = dir ? kn : on;
        int r = dir ? on : kn;
        if (lk < 2) {
          const float* ap = edge_attr + (size_t)e * 16 + lk * 8;
          float4 f0 = LDF4(ap), f1 = LDF4(ap + 4);
          union { ushort h[8]; bf16x8 v; } pk;
          pk.h[0] = f2bf(f0.x); pk.h[1] = f2bf(f0.y);
          pk.h[2] = f2bf(f0.z); pk.h[3] = f2bf(f0.w);
          pk.h[4] = f2bf(f1.x); pk.h[5] = f2bf(f1.y);
          pk.h[6] = f2bf(f1.z); pk.h[7] = f2bf(f1.w);
          a0N = pk.v;
          a1N = *reinterpret_cast<const bf16x8*>(xb + (size_t)s * 16 + lk * 8);
        } else {
          a0N = *reinterpret_cast<const bf16x8*>(xb + (size_t)r * 16 +
                                                 (lk - 2) * 8);
        }
      }
      // compute current tile
      if (lk == 0) nodeW[wid][lrow] = nbase + (int)(vC.x >> 21);
      f32x4 acc[4];
      #pragma unroll
      for (int nt = 0; nt < 4; ++nt) {
        acc[nt] = f32x4{ebi[nt], ebi[nt], ebi[nt], ebi[nt]};
        acc[nt] = __builtin_amdgcn_mfma_f32_16x16x32_bf16(a0C, b0[nt], acc[nt],
                                                          0, 0, 0);
        acc[nt] = __builtin_amdgcn_mfma_f32_16x16x32_bf16(a1C, b1[nt], acc[nt],
                                                          0, 0, 0);
      }
      int m0 = (l >> 4) * 4;
      #pragma unroll
      for (int nt = 0; nt < 4; ++nt) {
        #pragma unroll
        for (int reg = 0; reg < 4; ++reg) {
          Clds[wid][(m0 + reg) * 72 + nt * 16 + lrow] =
              fmaxf(acc[nt][reg], 0.f);
        }
      }
      // segmented sum (r19/r21-proven broadcast-LDS compare)
      int vc = min(16, cc - wt * 16);
      float accum = 0.f;
      int prev = nodeW[wid][0];
      for (int mm = 0; mm < vc; ++mm) {
        int nd = nodeW[wid][mm];
        float v = Clds[wid][mm * 72 + l];
        if (nd != prev) {
          atomicAdd(&sum[(size_t)prev * 64 + l], accum);
          accum = 0.f;
          prev = nd;
        }
        accum += v;
      }
      atomicAdd(&sum[(size_t)prev * 64 + l], accum);
      // rotate
      vC = vN; a0C = a0N; a1C = a1N;
    }
    __syncthreads();  // all waves done before next chunk overwrites stage/ord
  }
}

// ---- node block via MFMA + FUSED column-sum reduce.
__global__ __launch_bounds__(256, 2) void node_mfma_kernel(
    const float* __restrict__ sum_recv, const ushort* __restrict__ xb,
    const ushort* __restrict__ wnb_img, const float* __restrict__ nb_init,
    ushort* __restrict__ n_h, float* __restrict__ e_sum,
    float* __restrict__ n_sum, int N) {
  __shared__ ushort Alds[64 * 128];      // 16 KB (reused as f32 scratch later)
  __shared__ ushort Wlds[64 * 128];      // 16 KB
  __shared__ ushort Clds[4][16 * 72];    // 9 KB
  int t = threadIdx.x;
  int base = blockIdx.x * 64;
  {
    const uint4* src = reinterpret_cast<const uint4*>(wnb_img);
    uint4* dst = reinterpret_cast<uint4*>(Wlds);
    #pragma unroll
    for (int i = 0; i < 4; ++i) dst[t + 256 * i] = src[t + 256 * i];
  }
  {
    int m = t >> 2, part = t & 3;
    int n = base + m;
    bool val = n < N;
    if (part < 2) {
      #pragma unroll
      for (int q = 0; q < 4; ++q) {
        int c = part * 4 + q;
        union { ushort h[8]; uint4 qq; } pk;
        if (val) {
          const float* src = sum_recv + (size_t)n * 64 + c * 8;
          float4 f0 = LDF4(src), f1 = LDF4(src + 4);
          pk.h[0] = f2bf(f0.x); pk.h[1] = f2bf(f0.y);
          pk.h[2] = f2bf(f0.z); pk.h[3] = f2bf(f0.w);
          pk.h[4] = f2bf(f1.x); pk.h[5] = f2bf(f1.y);
          pk.h[6] = f2bf(f1.z); pk.h[7] = f2bf(f1.w);
        } else {
          pk.qq = uint4{0, 0, 0, 0};
        }
        *reinterpret_cast<uint4*>(&Alds[nswz(m, c)]) = pk.qq;
      }
    } else if (part == 2) {
      uint4 w0 = {0, 0, 0, 0}, w1 = {0, 0, 0, 0};
      if (val) {
        const uint4* xp = reinterpret_cast<const uint4*>(xb + (size_t)n * 16);
        w0 = xp[0]; w1 = xp[1];
      }
      *reinterpret_cast<uint4*>(&Alds[nswz(m, 8)]) = w0;
      *reinterpret_cast<uint4*>(&Alds[nswz(m, 9)]) = w1;
      *reinterpret_cast<uint4*>(&Alds[nswz(m, 10)]) = uint4{0, 0, 0, 0};
      *reinterpret_cast<uint4*>(&Alds[nswz(m, 11)]) = uint4{0, 0, 0, 0};
    } else {
      #pragma unroll
      for (int q = 0; q < 4; ++q)
        *reinterpret_cast<uint4*>(&Alds[nswz(m, 12 + q)]) = uint4{0, 0, 0, 0};
    }
  }
  __syncthreads();
  int wid = t >> 6, l = t & 63;
  int lrow = l & 15, lk = l >> 4;
  int arow = wid * 16 + lrow;
  bf16x8 afr[4];
  #pragma unroll
  for (int g = 0; g < 4; ++g)
    afr[g] = *reinterpret_cast<const bf16x8*>(&Alds[nswz(arow, g * 4 + lk)]);
  f32x4 acc[4];
  #pragma unroll
  for (int nt = 0; nt < 4; ++nt) {
    float nbi = nb_init[nt * 16 + lrow];
    acc[nt] = f32x4{nbi, nbi, nbi, nbi};
    #pragma unroll
    for (int g = 0; g < 4; ++g) {
      bf16x8 b = *reinterpret_cast<const bf16x8*>(
          &Wlds[nswz(nt * 16 + lrow, g * 4 + lk)]);
      acc[nt] =
          __builtin_amdgcn_mfma_f32_16x16x32_bf16(afr[g], b, acc[nt], 0, 0, 0);
    }
  }
  int m0 = (l >> 4) * 4;
  #pragma unroll
  for (int nt = 0; nt < 4; ++nt) {
    #pragma unroll
    for (int reg = 0; reg < 4; ++reg) {
      Clds[wid][(m0 + reg) * 72 + nt * 16 + lrow] =
          f2bf(fmaxf(acc[nt][reg], 0.f));
    }
  }
  __syncthreads();
  int sm = l >> 2, ch = l & 3;
  int gn = base + wid * 16 + sm;
  uint4 c0 = *reinterpret_cast<const uint4*>(&Clds[wid][sm * 72 + ch * 16]);
  uint4 c1 = *reinterpret_cast<const uint4*>(&Clds[wid][sm * 72 + ch * 16 + 8]);
  if (gn < N) {
    uint4* dst = reinterpret_cast<uint4*>(n_h + (size_t)gn * 64 + ch * 16);
    dst[0] = c0;
    dst[1] = c1;
  }
  // ---- fused reduce: per-block column sums of sum_recv (fp32) and n_h
  float* scr = reinterpret_cast<float*>(Alds);  // Alds free after afr loads
  {
    int col = t & 63, rg = t >> 6;
    float pe = 0.f, pn = 0.f;
    #pragma unroll
    for (int rr = 0; rr < 16; ++rr) {
      int n = base + rg * 16 + rr;
      if (n < N) {
        pe += sum_recv[(size_t)n * 64 + col];
        pn += __uint_as_float((uint)Clds[rg][rr * 72 + col] << 16);
      }
    }
    scr[rg * 64 + col] = pe;
    scr[256 + rg * 64 + col] = pn;
  }
  __syncthreads();
  if (t < 64) {
    float se = scr[t] + scr[64 + t] + scr[128 + t] + scr[192 + t];
    float sn = scr[256 + t] + scr[320 + t] + scr[384 + t] + scr[448 + t];
    atomicAdd(&e_sum[t], se);
    atomicAdd(&n_sum[t], sn);
  }
}

// ---- decoder via MFMA with FUSED global block (per-block redundant).
__global__ __launch_bounds__(256, 2) void decoder_mfma_kernel(
    const float* __restrict__ sum_recv, const float* __restrict__ sum_sent,
    const uint* __restrict__ cnt_r, const uint* __restrict__ cnt_s,
    const ushort* __restrict__ n_h, const ushort* __restrict__ wtd1_img,
    const ushort* __restrict__ w2_img, const float* __restrict__ b_d2,
    const float* __restrict__ u, const float* __restrict__ e_sum,
    const float* __restrict__ n_sum, const float* __restrict__ W_gb,
    const float* __restrict__ b_gb, const float* __restrict__ W_d1,
    const float* __restrict__ b_d1, float* __restrict__ out, float invE,
    float invN, int N) {
  __shared__ ushort Alds[64 * 192];   // 24 KB
  __shared__ ushort Wlds[64 * 192];   // 24 KB
  __shared__ ushort Hlds[64 * 64];    // 8 KB
  __shared__ ushort W2lds[16 * 64];   // 2 KB
  __shared__ float gin[192], u2s[64], d1i[64];
  int t = threadIdx.x;
  int base = blockIdx.x * 64;
  {
    const uint4* src = reinterpret_cast<const uint4*>(wtd1_img);
    uint4* dst = reinterpret_cast<uint4*>(Wlds);
    #pragma unroll
    for (int i = 0; i < 6; ++i) dst[t + 256 * i] = src[t + 256 * i];
    if (t < 128)
      reinterpret_cast<uint4*>(W2lds)[t] =
          reinterpret_cast<const uint4*>(w2_img)[t];
  }
  {
    int m = t >> 2;
    int n = base + m;
    bool val = n < N;
    float invr = 0.f, invs = 0.f;
    if (val) {
      invr = 1.f / fmaxf((float)cnt_r[n], 1.f);
      invs = 1.f / fmaxf((float)cnt_s[n], 1.f);
    }
    int c0 = (t & 3) * 6;
    for (int c = c0; c < c0 + 6; ++c) {
      union { ushort h[8]; uint4 q; } pk;
      if (val) {
        if (c >= 16) {
          pk.q = *reinterpret_cast<const uint4*>(n_h + (size_t)n * 64 +
                                                 (c - 16) * 8);
        } else {
          const float* src;
          float scl;
          if (c < 8) { src = sum_recv + (size_t)n * 64 + c * 8; scl = invr; }
          else       { src = sum_sent + (size_t)n * 64 + (c - 8) * 8; scl = invs; }
          float4 f0 = LDF4(src), f1 = LDF4(src + 4);
          pk.h[0] = f2bf(f0.x * scl); pk.h[1] = f2bf(f0.y * scl);
          pk.h[2] = f2bf(f0.z * scl); pk.h[3] = f2bf(f0.w * scl);
          pk.h[4] = f2bf(f1.x * scl); pk.h[5] = f2bf(f1.y * scl);
          pk.h[6] = f2bf(f1.z * scl); pk.h[7] = f2bf(f1.w * scl);
        }
      } else {
        pk.q = uint4{0, 0, 0, 0};
      }
      *reinterpret_cast<uint4*>(&Alds[aswz192(m, c)]) = pk.q;
    }
  }
  // fused global: gin -> u2 -> d1i (64 threads; small serial chains)
  if (t < 64) {
    gin[t] = e_sum[t] * invE;
    gin[64 + t] = n_sum[t] * invN;
    gin[128 + t] = u[t];
  }
  __syncthreads();
  if (t < 64) {
    float a = b_gb[t];
    for (int k = 0; k < 192; ++k) a = fmaf(gin[k], W_gb[k * 64 + t], a);
    u2s[t] = fmaxf(a, 0.f);
  }
  __syncthreads();
  if (t < 64) {
    float d = b_d1[t];
    for (int k = 0; k < 64; ++k) d = fmaf(u2s[k], W_d1[(192 + k) * 64 + t], d);
    d1i[t] = d;
  }
  __syncthreads();
  int wid = t >> 6, l = t & 63;
  int lrow = l & 15, lk = l >> 4;
  int arow = wid * 16 + lrow;
  bf16x8 afr[6];
  #pragma unroll
  for (int g = 0; g < 6; ++g)
    afr[g] = *reinterpret_cast<const bf16x8*>(&Alds[aswz192(arow, g * 4 + lk)]);
  f32x4 acc[4];
  #pragma unroll
  for (int nt = 0; nt < 4; ++nt) {
    float di = d1i[nt * 16 + lrow];
    acc[nt] = f32x4{di, di, di, di};
    #pragma unroll
    for (int g = 0; g < 6; ++g) {
      bf16x8 b = *reinterpret_cast<const bf16x8*>(
          &Wlds[aswz192(nt * 16 + lrow, g * 4 + lk)]);
      acc[nt] =
          __builtin_amdgcn_mfma_f32_16x16x32_bf16(afr[g], b, acc[nt], 0, 0, 0);
    }
  }
  int m0 = (l >> 4) * 4;
  #pragma unroll
  for (int nt = 0; nt < 4; ++nt) {
    #pragma unroll
    for (int reg = 0; reg < 4; ++reg) {
      int hm = wid * 16 + m0 + reg;
      int hn = nt * 16 + lrow;
      Hlds[hm * 64 + (((hn >> 3) ^ (hm & 7)) << 3) + (hn & 7)] =
          f2bf(fmaxf(acc[nt][reg], 0.f));
    }
  }
  __syncthreads();
  bf16x8 a20 = *reinterpret_cast<const bf16x8*>(&Hlds[aswz(arow, lk)]);
  bf16x8 a21 = *reinterpret_cast<const bf16x8*>(&Hlds[aswz(arow, 4 + lk)]);
  bf16x8 b20 = *reinterpret_cast<const bf16x8*>(&W2lds[aswz(lrow, lk)]);
  bf16x8 b21 = *reinterpret_cast<const bf16x8*>(&W2lds[aswz(lrow, 4 + lk)]);
  float bi = b_d2[lrow];
  f32x4 o = f32x4{bi, bi, bi, bi};
  o = __builtin_amdgcn_mfma_f32_16x16x32_bf16(a20, b20, o, 0, 0, 0);
  o = __builtin_amdgcn_mfma_f32_16x16x32_bf16(a21, b21, o, 0, 0, 0);
  #pragma unroll
  for (int reg = 0; reg < 4; ++reg) {
    int ge = base + wid * 16 + m0 + reg;
    if (ge < N) out[(size_t)ge * 16 + lrow] = o[reg];
  }
}

extern "C" void kernel_launch(void* const* d_in, const int* in_sizes, int n_in,
                              void* d_out, int out_size, void* d_ws,
                              size_t ws_size, hipStream_t stream) {
  const float* x         = (const float*)d_in[0];
  const float* edge_attr = (const float*)d_in[1];
  const float* u         = (const float*)d_in[2];
  const int*   senders   = (const int*)d_in[3];
  const int*   receivers = (const int*)d_in[4];
  const float* W_eb = (const float*)d_in[7];
  const float* b_eb = (const float*)d_in[8];
  const float* W_nb = (const float*)d_in[9];
  const float* b_nb = (const float*)d_in[10];
  const float* W_gb = (const float*)d_in[11];
  const float* b_gb = (const float*)d_in[12];
  const float* W_d1 = (const float*)d_in[13];
  const float* b_d1 = (const float*)d_in[14];
  const float* W_d2 = (const float*)d_in[15];
  const float* b_d2 = (const float*)d_in[16];

  int N = in_sizes[0] / 16;
  int E = in_sizes[1] / 16;
  int NB = (N + BW - 1) >> BSHIFT;  // 782 for N=100000
  int NDB = (E + DC - 1) / DC;      // distribute chunks per direction
  int nxb = (N * 16 / 4 + 255) / 256;

  char* w = (char*)d_ws;
  float* sum_recv = (float*)w;       w += (size_t)N * 64 * 4;
  float* sum_sent = (float*)w;       w += (size_t)N * 64 * 4;
  ushort* n_h = (ushort*)w;          w += (size_t)N * 64 * 2;
  uint2* tmp_r = (uint2*)w;          w += (size_t)E * 8;
  uint2* tmp_s = (uint2*)w;          w += (size_t)E * 8;
  ushort* xb = (ushort*)w;           w += (size_t)N * 16 * 2;
  ushort* wt_lin = (ushort*)w;       w += (size_t)64 * 64 * 2;
  ushort* wnb_img = (ushort*)w;      w += (size_t)64 * 128 * 2;
  ushort* wtd1_img = (ushort*)w;     w += (size_t)64 * 192 * 2;
  ushort* w2_img = (ushort*)w;       w += (size_t)16 * 64 * 2;
  uint* start_r = (uint*)w;          w += (size_t)(NB + 1) * 4;
  uint* start_s = (uint*)w;          w += (size_t)(NB + 1) * 4;
  uint* cur_r = (uint*)w;            w += (size_t)NB * 4;
  uint* cur_s = (uint*)w;            w += (size_t)NB * 4;
  // zeroed region: cnt_r, cnt_s, bcnt_r, bcnt_s, e_sum, n_sum
  uint* cnt_r = (uint*)w;            w += (size_t)N * 4;
  uint* cnt_s = (uint*)w;            w += (size_t)N * 4;
  uint* bcnt_r = (uint*)w;           w += (size_t)NBMAX * 4;
  uint* bcnt_s = (uint*)w;           w += (size_t)NBMAX * 4;
  float* e_sum = (float*)w;          w += 64 * 4;
  float* n_sum = (float*)w;          w += 64 * 4;
  // small non-zeroed
  float* eb_init = (float*)w;        w += 64 * 4;
  float* nb_init = (float*)w;        w += 64 * 4;

  size_t zero_bytes = ((size_t)2 * N + 2 * NBMAX + 128) * 4;
  hipMemsetAsync(cnt_r, 0, zero_bytes, stream);
  hipMemsetAsync(sum_recv, 0, (size_t)N * 128 * 4, stream);

  hipLaunchKernelGGL(init_kernel, dim3(1 + nxb + 64), dim3(256), 0, stream, x,
                     xb, N * 16, nxb, receivers, senders, bcnt_r, bcnt_s, E,
                     NB, u, W_eb, b_eb, W_nb, b_nb, W_d1, W_d2, eb_init,
                     nb_init, wt_lin, wnb_img, wtd1_img, w2_img);
  hipLaunchKernelGGL(bscan_kernel, dim3(1), dim3(256), 0, stream, bcnt_r,
                     bcnt_s, start_r, start_s, cur_r, cur_s, E, NB);
  hipLaunchKernelGGL(distribute_kernel, dim3(2 * NDB), dim3(256), 0, stream,
                     receivers, senders, cur_r, cur_s, tmp_r, tmp_s, E, NB);
  hipLaunchKernelGGL(escatter_kernel, dim3(2 * NB), dim3(256), 0, stream,
                     edge_attr, xb, tmp_r, tmp_s, start_r, start_s, wt_lin,
                     eb_init, sum_recv, sum_sent, cnt_r, cnt_s, E, N);
  hipLaunchKernelGGL(node_mfma_kernel, dim3((N + 63) / 64), dim3(256), 0,
                     stream, sum_recv, xb, wnb_img, nb_init, n_h, e_sum,
                     n_sum, N);
  hipLaunchKernelGGL(decoder_mfma_kernel, dim3((N + 63) / 64), dim3(256), 0,
                     stream, sum_recv, sum_sent, cnt_r, cnt_s, n_h, wtd1_img,
                     w2_img, b_d2, u, e_sum, n_sum, W_gb, b_gb, W_d1, b_d1,
                     (float*)d_out, 1.0f / (float)E, 1.0f / (float)N, N);
}

// Round 23
// 393.898 us; speedup vs baseline: 1.0520x; 1.0520x over previous
//
#include <hip/hip_runtime.h>

// GraphNet forward. Round 23: revert to r21 (measured best, 398us).
// r22's sort-into-escatter fusion regressed (+38us in escatter vs -40us
// launch saved: LDS 19->35KB cut occupancy 49->36%, added barriers +
// bank conflicts). r21 = r19 escatter (2-deep pipeline, packed uint2,
// per-row segmented sum) + r20 fusions (init+bcount, node+reduce,
// decoder+global).

typedef unsigned int uint;
typedef unsigned short ushort;
typedef __attribute__((ext_vector_type(8))) short bf16x8;
typedef __attribute__((ext_vector_type(4))) float f32x4;

#define BW 128          // nodes per bucket (sort)
#define BSHIFT 7
#define NBMAX 784       // max buckets (N=100000 -> 782)
#define DC 4096         // edges per distribute block (uint2 staging)
#define EMASK 0x1FFFFFu // 21 bits of edge id
#define OMASK 0x1FFFFu  // 17 bits of other-node id

#define LDF4(p) (*reinterpret_cast<const float4*>(p))

__device__ __forceinline__ ushort f2bf(float f) {
  uint u = __float_as_uint(f);
  u += 0x7FFFu + ((u >> 16) & 1u);
  return (ushort)(u >> 16);
}

// swizzled ushort index of 16B chunk (row, kb) in [row][64] bf16 tile
__device__ __forceinline__ int aswz(int row, int kb) {
  return row * 64 + ((kb ^ (row & 7)) << 3);
}
// [row][128] tile (kb 0..15)
__device__ __forceinline__ int nswz(int row, int kb) {
  return row * 128 + (((kb & 8) | ((kb ^ row) & 7)) << 3);
}
// [row][192] tile (kb 0..23)
__device__ __forceinline__ int aswz192(int row, int kb) {
  return row * 192 + (((kb & 24) | ((kb ^ row) & 7)) << 3);
}

// ---- merged init: weights (block 0) + x->bf16 (blocks 1..nxb) +
//      bucket histogram (last 64 blocks)
__global__ __launch_bounds__(256) void init_kernel(
    const float* __restrict__ x, ushort* __restrict__ xb, int n16, int nxb,
    const int* __restrict__ receivers, const int* __restrict__ senders,
    uint* __restrict__ bcnt_r, uint* __restrict__ bcnt_s, int E, int NB,
    const float* __restrict__ u, const float* __restrict__ W_eb,
    const float* __restrict__ b_eb, const float* __restrict__ W_nb,
    const float* __restrict__ b_nb, const float* __restrict__ W_d1,
    const float* __restrict__ W_d2, float* __restrict__ eb_init,
    float* __restrict__ nb_init, ushort* __restrict__ wt_lin,
    ushort* __restrict__ wnb_img, ushort* __restrict__ wtd1_img,
    ushort* __restrict__ w2_img) {
  if (blockIdx.x == 0) {
    int j = threadIdx.x;
    if (j >= 64) return;
    float ae = b_eb[j], an = b_nb[j];
    for (int k = 0; k < 64; ++k) {
      float uk = u[k];
      ae = fmaf(uk, W_eb[(48 + k) * 64 + j], ae);
      an = fmaf(uk, W_nb[(80 + k) * 64 + j], an);
    }
    eb_init[j] = ae;
    nb_init[j] = an;
    for (int k = 0; k < 64; ++k)
      wt_lin[j * 64 + k] = (k < 48) ? f2bf(W_eb[k * 64 + j]) : (ushort)0;
    for (int k = 0; k < 128; ++k) {
      ushort v = (k < 80) ? f2bf(W_nb[k * 64 + j]) : (ushort)0;
      wnb_img[nswz(j, k >> 3) + (k & 7)] = v;
    }
    for (int k = 0; k < 192; ++k)
      wtd1_img[aswz192(j, k >> 3) + (k & 7)] = f2bf(W_d1[k * 64 + j]);
    if (j < 16)
      for (int k = 0; k < 64; ++k)
        w2_img[aswz(j, k >> 3) + (k & 7)] = f2bf(W_d2[k * 16 + j]);
    return;
  }
  if (blockIdx.x <= nxb) {
    int i = (blockIdx.x - 1) * 256 + threadIdx.x;
    if (i * 4 >= n16) return;
    float4 a = LDF4(x + i * 4);
    ushort4 o = {f2bf(a.x), f2bf(a.y), f2bf(a.z), f2bf(a.w)};
    *reinterpret_cast<ushort4*>(xb + i * 4) = o;
    return;
  }
  // bucket histogram (64 blocks)
  __shared__ uint hr[NBMAX], hs[NBMAX];
  int t = threadIdx.x;
  int bid = blockIdx.x - 1 - nxb;
  for (int i = t; i < NB; i += 256) { hr[i] = 0; hs[i] = 0; }
  __syncthreads();
  int stride = 64 * 256;
  for (int e = bid * 256 + t; e < E; e += stride) {
    atomicAdd(&hr[receivers[e] >> BSHIFT], 1u);
    atomicAdd(&hs[senders[e] >> BSHIFT], 1u);
  }
  __syncthreads();
  for (int i = t; i < NB; i += 256) {
    if (hr[i]) atomicAdd(&bcnt_r[i], hr[i]);
    if (hs[i]) atomicAdd(&bcnt_s[i], hs[i]);
  }
}

// ---- exclusive scan of both bucket-count arrays (single block, 4/thread)
__global__ __launch_bounds__(256) void bscan_kernel(
    const uint* __restrict__ bcnt_r, const uint* __restrict__ bcnt_s,
    uint* __restrict__ start_r, uint* __restrict__ start_s,
    uint* __restrict__ cur_r, uint* __restrict__ cur_s, int E, int NB) {
  __shared__ uint ts[256];
  int t = threadIdx.x;
  #pragma unroll
  for (int pass = 0; pass < 2; ++pass) {
    const uint* cnt = pass ? bcnt_s : bcnt_r;
    uint* start = pass ? start_s : start_r;
    uint* cur = pass ? cur_s : cur_r;
    uint loc[4]; uint tsum = 0;
    #pragma unroll
    for (int q = 0; q < 4; ++q) {
      int i = t * 4 + q;
      loc[q] = (i < NB) ? cnt[i] : 0;
      tsum += loc[q];
    }
    ts[t] = tsum;
    __syncthreads();
    for (int off = 1; off < 256; off <<= 1) {
      uint a = (t >= off) ? ts[t - off] : 0;
      __syncthreads();
      ts[t] += a;
      __syncthreads();
    }
    uint run = ts[t] - tsum;
    #pragma unroll
    for (int q = 0; q < 4; ++q) {
      int i = t * 4 + q;
      if (i < NB) { start[i] = run; cur[i] = run; run += loc[q]; }
    }
    if (t == 0) start[NB] = (uint)E;
    __syncthreads();
  }
}

// ---- bucket-sort, both directions; entry = {(nl<<21)|edge, other_node}
__global__ __launch_bounds__(256) void distribute_kernel(
    const int* __restrict__ receivers, const int* __restrict__ senders,
    uint* __restrict__ gcur_r, uint* __restrict__ gcur_s,
    uint2* __restrict__ tmp_r, uint2* __restrict__ tmp_s, int E, int NB) {
  __shared__ uint hist[NBMAX], lstart[NBMAX], cur[NBMAX], gbase[NBMAX];
  __shared__ uint2 ids[DC];           // 32 KB
  __shared__ ushort idsB[DC];         // 8 KB
  __shared__ uint ts[256];
  int dir = blockIdx.x & 1;
  const int* key = dir ? senders : receivers;
  const int* oth = dir ? receivers : senders;
  uint* g_cursor = dir ? gcur_s : gcur_r;
  uint2* tmp = dir ? tmp_s : tmp_r;
  int t = threadIdx.x;
  int base = (blockIdx.x >> 1) * DC;
  int cact = min(DC, E - base);
  for (int i = t; i < NB; i += 256) hist[i] = 0;
  __syncthreads();
  for (int k = 0; k < DC / 256; ++k) {
    int j = k * 256 + t;
    if (j < cact) atomicAdd(&hist[key[base + j] >> BSHIFT], 1u);
  }
  __syncthreads();
  {
    uint loc[4]; uint tsum = 0;
    #pragma unroll
    for (int q = 0; q < 4; ++q) {
      int i = t * 4 + q;
      loc[q] = (i < NB) ? hist[i] : 0;
      tsum += loc[q];
    }
    ts[t] = tsum;
    __syncthreads();
    for (int off = 1; off < 256; off <<= 1) {
      uint a = (t >= off) ? ts[t - off] : 0;
      __syncthreads();
      ts[t] += a;
      __syncthreads();
    }
    uint run = ts[t] - tsum;
    #pragma unroll
    for (int q = 0; q < 4; ++q) {
      int i = t * 4 + q;
      if (i < NB) { lstart[i] = run; cur[i] = run; run += loc[q]; }
    }
  }
  __syncthreads();
  for (int i = t; i < NB; i += 256)
    if (hist[i]) gbase[i] = atomicAdd(&g_cursor[i], hist[i]);
  for (int k = 0; k < DC / 256; ++k) {
    int j = k * 256 + t;
    if (j < cact) {
      int e = base + j;
      int kk = key[e];
      uint b = (uint)(kk >> BSHIFT);
      uint slot = atomicAdd(&cur[b], 1u);
      ids[slot] = uint2{((uint)(kk & (BW - 1)) << 21) | (uint)e,
                        (uint)oth[e]};
      idsB[slot] = (ushort)b;
    }
  }
  __syncthreads();
  for (int j = t; j < cact; j += 256) {
    uint b2 = idsB[j];
    tmp[gbase[b2] + ((uint)j - lstart[b2])] = ids[j];
  }
}

// ---- per-bucket counting sort; emits ONE packed uint2 stream:
// {.x=(nl<<21)|edge, .y=(bucket<<17)|other}
__global__ __launch_bounds__(256) void bucketsort_kernel(
    const uint2* __restrict__ tmp_r, const uint2* __restrict__ tmp_s,
    const uint* __restrict__ start_r, const uint* __restrict__ start_s,
    uint2* __restrict__ srt_r, uint2* __restrict__ srt_s,
    uint* __restrict__ cnt_r, uint* __restrict__ cnt_s, int N) {
  __shared__ uint hist[BW], pfx[BW], cur[BW];
  int d = blockIdx.x & 1;
  int b = blockIdx.x >> 1;
  const uint2* tmp = d ? tmp_s : tmp_r;
  const uint* start = d ? start_s : start_r;
  uint2* srt = d ? srt_s : srt_r;
  uint* cnt = d ? cnt_s : cnt_r;
  int t = threadIdx.x;
  if (t < BW) hist[t] = 0;
  __syncthreads();
  int beg = (int)start[b], end = (int)start[b + 1];
  for (int i = beg + t; i < end; i += 256)
    atomicAdd(&hist[tmp[i].x >> 21], 1u);
  __syncthreads();
  if (t < BW) pfx[t] = hist[t];
  __syncthreads();
  for (int off = 1; off < BW; off <<= 1) {
    uint a = 0;
    if (t < BW && t >= off) a = pfx[t - off];
    __syncthreads();
    if (t < BW) pfx[t] += a;
    __syncthreads();
  }
  if (t < BW) cur[t] = pfx[t] - hist[t];
  __syncthreads();
  uint bhi = (uint)b << 17;
  for (int i = beg + t; i < end; i += 256) {
    uint2 v = tmp[i];
    uint nl = v.x >> 21;
    uint p = beg + atomicAdd(&cur[nl], 1u);
    srt[p] = uint2{v.x, bhi | v.y};
  }
  int nbase = b * BW;
  if (t < BW && nbase + t < N) cnt[nbase + t] = hist[t];
}

// ---- FUSED edge-MLP + aggregation, 2-deep pipeline (r19 segmented sum).
__global__ __launch_bounds__(256, 4) void escatter_kernel(
    const float* __restrict__ edge_attr, const ushort* __restrict__ xb,
    const uint2* __restrict__ srt_r, const uint2* __restrict__ srt_s,
    const ushort* __restrict__ wt_lin, const float* __restrict__ eb_init,
    float* __restrict__ sum_recv, float* __restrict__ sum_sent, int E,
    int ntiles) {
  __shared__ float Clds[4][16 * 72];  // fp32, wave-local
  __shared__ int nodeW[4][16];
  int t = threadIdx.x;
  int wid = t >> 6, l = t & 63;
  int lrow = l & 15, lk = l >> 4;
  bf16x8 b0[4], b1[4];
  float ebi[4];
  #pragma unroll
  for (int nt = 0; nt < 4; ++nt) {
    const ushort* wr = wt_lin + (nt * 16 + lrow) * 64;
    b0[nt] = *reinterpret_cast<const bf16x8*>(wr + lk * 8);
    b1[nt] = *reinterpret_cast<const bf16x8*>(wr + 32 + lk * 8);
    ebi[nt] = eb_init[nt * 16 + lrow];
  }
  const bf16x8 zero8 = {0, 0, 0, 0, 0, 0, 0, 0};
  int dir = blockIdx.x & 1;
  const uint2* srt = dir ? srt_s : srt_r;
  float* sum = dir ? sum_sent : sum_recv;
  int gw = (blockIdx.x >> 1) * 4 + wid;
  int nw = (gridDim.x >> 1) * 4;

  uint2 vC = {0, 0}, vN = {0, 0};
  bf16x8 a0C = zero8, a1C = zero8;

  if (gw < ntiles) {
    vC = srt[min(gw * 16 + lrow, E - 1)];
    int e = (int)(vC.x & EMASK);
    int kn = (int)((vC.y >> 17) * BW + (vC.x >> 21));
    int on = (int)(vC.y & OMASK);
    int s = dir ? kn : on;
    int r = dir ? on : kn;
    if (lk < 2) {
      const float* ap = edge_attr + (size_t)e * 16 + lk * 8;
      float4 f0 = LDF4(ap), f1 = LDF4(ap + 4);
      union { ushort h[8]; bf16x8 v; } pk;
      pk.h[0] = f2bf(f0.x); pk.h[1] = f2bf(f0.y);
      pk.h[2] = f2bf(f0.z); pk.h[3] = f2bf(f0.w);
      pk.h[4] = f2bf(f1.x); pk.h[5] = f2bf(f1.y);
      pk.h[6] = f2bf(f1.z); pk.h[7] = f2bf(f1.w);
      a0C = pk.v;
      a1C = *reinterpret_cast<const bf16x8*>(xb + (size_t)s * 16 + lk * 8);
    } else {
      a0C = *reinterpret_cast<const bf16x8*>(xb + (size_t)r * 16 +
                                             (lk - 2) * 8);
      a1C = zero8;
    }
  }
  if (gw + nw < ntiles) vN = srt[min((gw + nw) * 16 + lrow, E - 1)];

  for (int tile = gw; tile < ntiles; tile += nw) {
    bool hasN = (tile + nw) < ntiles;
    bool has2 = (tile + 2 * nw) < ntiles;
    bf16x8 a0N = zero8, a1N = zero8;
    if (hasN) {
      int e = (int)(vN.x & EMASK);
      int kn = (int)((vN.y >> 17) * BW + (vN.x >> 21));
      int on = (int)(vN.y & OMASK);
      int s = dir ? kn : on;
      int r = dir ? on : kn;
      if (lk < 2) {
        const float* ap = edge_attr + (size_t)e * 16 + lk * 8;
        float4 f0 = LDF4(ap), f1 = LDF4(ap + 4);
        union { ushort h[8]; bf16x8 v; } pk;
        pk.h[0] = f2bf(f0.x); pk.h[1] = f2bf(f0.y);
        pk.h[2] = f2bf(f0.z); pk.h[3] = f2bf(f0.w);
        pk.h[4] = f2bf(f1.x); pk.h[5] = f2bf(f1.y);
        pk.h[6] = f2bf(f1.z); pk.h[7] = f2bf(f1.w);
        a0N = pk.v;
        a1N = *reinterpret_cast<const bf16x8*>(xb + (size_t)s * 16 + lk * 8);
      } else {
        a0N = *reinterpret_cast<const bf16x8*>(xb + (size_t)r * 16 +
                                               (lk - 2) * 8);
      }
    }
    uint2 v2 = {0, 0};
    if (has2) v2 = srt[min((tile + 2 * nw) * 16 + lrow, E - 1)];
    // compute current tile
    if (lk == 0)
      nodeW[wid][lrow] = (int)((vC.y >> 17) * BW + (vC.x >> 21));
    f32x4 acc[4];
    #pragma unroll
    for (int nt = 0; nt < 4; ++nt) {
      acc[nt] = f32x4{ebi[nt], ebi[nt], ebi[nt], ebi[nt]};
      acc[nt] =
          __builtin_amdgcn_mfma_f32_16x16x32_bf16(a0C, b0[nt], acc[nt], 0, 0, 0);
      acc[nt] =
          __builtin_amdgcn_mfma_f32_16x16x32_bf16(a1C, b1[nt], acc[nt], 0, 0, 0);
    }
    int m0 = (l >> 4) * 4;
    #pragma unroll
    for (int nt = 0; nt < 4; ++nt) {
      #pragma unroll
      for (int reg = 0; reg < 4; ++reg) {
        Clds[wid][(m0 + reg) * 72 + nt * 16 + lrow] =
            fmaxf(acc[nt][reg], 0.f);
      }
    }
    // r19 segmented sum: per-row broadcast-LDS compare
    int vc = min(16, E - tile * 16);
    float accum = 0.f;
    int prev = nodeW[wid][0];
    for (int mm = 0; mm < vc; ++mm) {
      int nd = nodeW[wid][mm];
      float v = Clds[wid][mm * 72 + l];
      if (nd != prev) {
        atomicAdd(&sum[(size_t)prev * 64 + l], accum);
        accum = 0.f;
        prev = nd;
      }
      accum += v;
    }
    atomicAdd(&sum[(size_t)prev * 64 + l], accum);
    // rotate
    vC = vN; a0C = a0N; a1C = a1N; vN = v2;
  }
}

// ---- node block via MFMA + FUSED column-sum reduce.
__global__ __launch_bounds__(256, 2) void node_mfma_kernel(
    const float* __restrict__ sum_recv, const ushort* __restrict__ xb,
    const ushort* __restrict__ wnb_img, const float* __restrict__ nb_init,
    ushort* __restrict__ n_h, float* __restrict__ e_sum,
    float* __restrict__ n_sum, int N) {
  __shared__ ushort Alds[64 * 128];      // 16 KB (reused as f32 scratch later)
  __shared__ ushort Wlds[64 * 128];      // 16 KB
  __shared__ ushort Clds[4][16 * 72];    // 9 KB
  int t = threadIdx.x;
  int base = blockIdx.x * 64;
  {
    const uint4* src = reinterpret_cast<const uint4*>(wnb_img);
    uint4* dst = reinterpret_cast<uint4*>(Wlds);
    #pragma unroll
    for (int i = 0; i < 4; ++i) dst[t + 256 * i] = src[t + 256 * i];
  }
  {
    int m = t >> 2, part = t & 3;
    int n = base + m;
    bool val = n < N;
    if (part < 2) {
      #pragma unroll
      for (int q = 0; q < 4; ++q) {
        int c = part * 4 + q;
        union { ushort h[8]; uint4 qq; } pk;
        if (val) {
          const float* src = sum_recv + (size_t)n * 64 + c * 8;
          float4 f0 = LDF4(src), f1 = LDF4(src + 4);
          pk.h[0] = f2bf(f0.x); pk.h[1] = f2bf(f0.y);
          pk.h[2] = f2bf(f0.z); pk.h[3] = f2bf(f0.w);
          pk.h[4] = f2bf(f1.x); pk.h[5] = f2bf(f1.y);
          pk.h[6] = f2bf(f1.z); pk.h[7] = f2bf(f1.w);
        } else {
          pk.qq = uint4{0, 0, 0, 0};
        }
        *reinterpret_cast<uint4*>(&Alds[nswz(m, c)]) = pk.qq;
      }
    } else if (part == 2) {
      uint4 w0 = {0, 0, 0, 0}, w1 = {0, 0, 0, 0};
      if (val) {
        const uint4* xp = reinterpret_cast<const uint4*>(xb + (size_t)n * 16);
        w0 = xp[0]; w1 = xp[1];
      }
      *reinterpret_cast<uint4*>(&Alds[nswz(m, 8)]) = w0;
      *reinterpret_cast<uint4*>(&Alds[nswz(m, 9)]) = w1;
      *reinterpret_cast<uint4*>(&Alds[nswz(m, 10)]) = uint4{0, 0, 0, 0};
      *reinterpret_cast<uint4*>(&Alds[nswz(m, 11)]) = uint4{0, 0, 0, 0};
    } else {
      #pragma unroll
      for (int q = 0; q < 4; ++q)
        *reinterpret_cast<uint4*>(&Alds[nswz(m, 12 + q)]) = uint4{0, 0, 0, 0};
    }
  }
  __syncthreads();
  int wid = t >> 6, l = t & 63;
  int lrow = l & 15, lk = l >> 4;
  int arow = wid * 16 + lrow;
  bf16x8 afr[4];
  #pragma unroll
  for (int g = 0; g < 4; ++g)
    afr[g] = *reinterpret_cast<const bf16x8*>(&Alds[nswz(arow, g * 4 + lk)]);
  f32x4 acc[4];
  #pragma unroll
  for (int nt = 0; nt < 4; ++nt) {
    float nbi = nb_init[nt * 16 + lrow];
    acc[nt] = f32x4{nbi, nbi, nbi, nbi};
    #pragma unroll
    for (int g = 0; g < 4; ++g) {
      bf16x8 b = *reinterpret_cast<const bf16x8*>(
          &Wlds[nswz(nt * 16 + lrow, g * 4 + lk)]);
      acc[nt] =
          __builtin_amdgcn_mfma_f32_16x16x32_bf16(afr[g], b, acc[nt], 0, 0, 0);
    }
  }
  int m0 = (l >> 4) * 4;
  #pragma unroll
  for (int nt = 0; nt < 4; ++nt) {
    #pragma unroll
    for (int reg = 0; reg < 4; ++reg) {
      Clds[wid][(m0 + reg) * 72 + nt * 16 + lrow] =
          f2bf(fmaxf(acc[nt][reg], 0.f));
    }
  }
  __syncthreads();
  int sm = l >> 2, ch = l & 3;
  int gn = base + wid * 16 + sm;
  uint4 c0 = *reinterpret_cast<const uint4*>(&Clds[wid][sm * 72 + ch * 16]);
  uint4 c1 = *reinterpret_cast<const uint4*>(&Clds[wid][sm * 72 + ch * 16 + 8]);
  if (gn < N) {
    uint4* dst = reinterpret_cast<uint4*>(n_h + (size_t)gn * 64 + ch * 16);
    dst[0] = c0;
    dst[1] = c1;
  }
  // ---- fused reduce: per-block column sums of sum_recv (fp32) and n_h
  float* scr = reinterpret_cast<float*>(Alds);  // Alds free after afr loads
  {
    int col = t & 63, rg = t >> 6;
    float pe = 0.f, pn = 0.f;
    #pragma unroll
    for (int rr = 0; rr < 16; ++rr) {
      int n = base + rg * 16 + rr;
      if (n < N) {
        pe += sum_recv[(size_t)n * 64 + col];
        pn += __uint_as_float((uint)Clds[rg][rr * 72 + col] << 16);
      }
    }
    scr[rg * 64 + col] = pe;
    scr[256 + rg * 64 + col] = pn;
  }
  __syncthreads();
  if (t < 64) {
    float se = scr[t] + scr[64 + t] + scr[128 + t] + scr[192 + t];
    float sn = scr[256 + t] + scr[320 + t] + scr[384 + t] + scr[448 + t];
    atomicAdd(&e_sum[t], se);
    atomicAdd(&n_sum[t], sn);
  }
}

// ---- decoder via MFMA with FUSED global block (per-block redundant).
__global__ __launch_bounds__(256, 2) void decoder_mfma_kernel(
    const float* __restrict__ sum_recv, const float* __restrict__ sum_sent,
    const uint* __restrict__ cnt_r, const uint* __restrict__ cnt_s,
    const ushort* __restrict__ n_h, const ushort* __restrict__ wtd1_img,
    const ushort* __restrict__ w2_img, const float* __restrict__ b_d2,
    const float* __restrict__ u, const float* __restrict__ e_sum,
    const float* __restrict__ n_sum, const float* __restrict__ W_gb,
    const float* __restrict__ b_gb, const float* __restrict__ W_d1,
    const float* __restrict__ b_d1, float* __restrict__ out, float invE,
    float invN, int N) {
  __shared__ ushort Alds[64 * 192];   // 24 KB
  __shared__ ushort Wlds[64 * 192];   // 24 KB
  __shared__ ushort Hlds[64 * 64];    // 8 KB
  __shared__ ushort W2lds[16 * 64];   // 2 KB
  __shared__ float gin[192], u2s[64], d1i[64];
  int t = threadIdx.x;
  int base = blockIdx.x * 64;
  {
    const uint4* src = reinterpret_cast<const uint4*>(wtd1_img);
    uint4* dst = reinterpret_cast<uint4*>(Wlds);
    #pragma unroll
    for (int i = 0; i < 6; ++i) dst[t + 256 * i] = src[t + 256 * i];
    if (t < 128)
      reinterpret_cast<uint4*>(W2lds)[t] =
          reinterpret_cast<const uint4*>(w2_img)[t];
  }
  {
    int m = t >> 2;
    int n = base + m;
    bool val = n < N;
    float invr = 0.f, invs = 0.f;
    if (val) {
      invr = 1.f / fmaxf((float)cnt_r[n], 1.f);
      invs = 1.f / fmaxf((float)cnt_s[n], 1.f);
    }
    int c0 = (t & 3) * 6;
    for (int c = c0; c < c0 + 6; ++c) {
      union { ushort h[8]; uint4 q; } pk;
      if (val) {
        if (c >= 16) {
          pk.q = *reinterpret_cast<const uint4*>(n_h + (size_t)n * 64 +
                                                 (c - 16) * 8);
        } else {
          const float* src;
          float scl;
          if (c < 8) { src = sum_recv + (size_t)n * 64 + c * 8; scl = invr; }
          else       { src = sum_sent + (size_t)n * 64 + (c - 8) * 8; scl = invs; }
          float4 f0 = LDF4(src), f1 = LDF4(src + 4);
          pk.h[0] = f2bf(f0.x * scl); pk.h[1] = f2bf(f0.y * scl);
          pk.h[2] = f2bf(f0.z * scl); pk.h[3] = f2bf(f0.w * scl);
          pk.h[4] = f2bf(f1.x * scl); pk.h[5] = f2bf(f1.y * scl);
          pk.h[6] = f2bf(f1.z * scl); pk.h[7] = f2bf(f1.w * scl);
        }
      } else {
        pk.q = uint4{0, 0, 0, 0};
      }
      *reinterpret_cast<uint4*>(&Alds[aswz192(m, c)]) = pk.q;
    }
  }
  // fused global: gin -> u2 -> d1i (64 threads; small serial chains)
  if (t < 64) {
    gin[t] = e_sum[t] * invE;
    gin[64 + t] = n_sum[t] * invN;
    gin[128 + t] = u[t];
  }
  __syncthreads();
  if (t < 64) {
    float a = b_gb[t];
    for (int k = 0; k < 192; ++k) a = fmaf(gin[k], W_gb[k * 64 + t], a);
    u2s[t] = fmaxf(a, 0.f);
  }
  __syncthreads();
  if (t < 64) {
    float d = b_d1[t];
    for (int k = 0; k < 64; ++k) d = fmaf(u2s[k], W_d1[(192 + k) * 64 + t], d);
    d1i[t] = d;
  }
  __syncthreads();
  int wid = t >> 6, l = t & 63;
  int lrow = l & 15, lk = l >> 4;
  int arow = wid * 16 + lrow;
  bf16x8 afr[6];
  #pragma unroll
  for (int g = 0; g < 6; ++g)
    afr[g] = *reinterpret_cast<const bf16x8*>(&Alds[aswz192(arow, g * 4 + lk)]);
  f32x4 acc[4];
  #pragma unroll
  for (int nt = 0; nt < 4; ++nt) {
    float di = d1i[nt * 16 + lrow];
    acc[nt] = f32x4{di, di, di, di};
    #pragma unroll
    for (int g = 0; g < 6; ++g) {
      bf16x8 b = *reinterpret_cast<const bf16x8*>(
          &Wlds[aswz192(nt * 16 + lrow, g * 4 + lk)]);
      acc[nt] =
          __builtin_amdgcn_mfma_f32_16x16x32_bf16(afr[g], b, acc[nt], 0, 0, 0);
    }
  }
  int m0 = (l >> 4) * 4;
  #pragma unroll
  for (int nt = 0; nt < 4; ++nt) {
    #pragma unroll
    for (int reg = 0; reg < 4; ++reg) {
      int hm = wid * 16 + m0 + reg;
      int hn = nt * 16 + lrow;
      Hlds[hm * 64 + (((hn >> 3) ^ (hm & 7)) << 3) + (hn & 7)] =
          f2bf(fmaxf(acc[nt][reg], 0.f));
    }
  }
  __syncthreads();
  bf16x8 a20 = *reinterpret_cast<const bf16x8*>(&Hlds[aswz(arow, lk)]);
  bf16x8 a21 = *reinterpret_cast<const bf16x8*>(&Hlds[aswz(arow, 4 + lk)]);
  bf16x8 b20 = *reinterpret_cast<const bf16x8*>(&W2lds[aswz(lrow, lk)]);
  bf16x8 b21 = *reinterpret_cast<const bf16x8*>(&W2lds[aswz(lrow, 4 + lk)]);
  float bi = b_d2[lrow];
  f32x4 o = f32x4{bi, bi, bi, bi};
  o = __builtin_amdgcn_mfma_f32_16x16x32_bf16(a20, b20, o, 0, 0, 0);
  o = __builtin_amdgcn_mfma_f32_16x16x32_bf16(a21, b21, o, 0, 0, 0);
  #pragma unroll
  for (int reg = 0; reg < 4; ++reg) {
    int ge = base + wid * 16 + m0 + reg;
    if (ge < N) out[(size_t)ge * 16 + lrow] = o[reg];
  }
}

extern "C" void kernel_launch(void* const* d_in, const int* in_sizes, int n_in,
                              void* d_out, int out_size, void* d_ws,
                              size_t ws_size, hipStream_t stream) {
  const float* x         = (const float*)d_in[0];
  const float* edge_attr = (const float*)d_in[1];
  const float* u         = (const float*)d_in[2];
  const int*   senders   = (const int*)d_in[3];
  const int*   receivers = (const int*)d_in[4];
  const float* W_eb = (const float*)d_in[7];
  const float* b_eb = (const float*)d_in[8];
  const float* W_nb = (const float*)d_in[9];
  const float* b_nb = (const float*)d_in[10];
  const float* W_gb = (const float*)d_in[11];
  const float* b_gb = (const float*)d_in[12];
  const float* W_d1 = (const float*)d_in[13];
  const float* b_d1 = (const float*)d_in[14];
  const float* W_d2 = (const float*)d_in[15];
  const float* b_d2 = (const float*)d_in[16];

  int N = in_sizes[0] / 16;
  int E = in_sizes[1] / 16;
  int NB = (N + BW - 1) >> BSHIFT;  // 782 for N=100000
  int NDB = (E + DC - 1) / DC;      // distribute chunks per direction
  int ntiles = (E + 15) / 16;
  int nxb = (N * 16 / 4 + 255) / 256;

  char* w = (char*)d_ws;
  float* sum_recv = (float*)w;       w += (size_t)N * 64 * 4;
  float* sum_sent = (float*)w;       w += (size_t)N * 64 * 4;
  ushort* n_h = (ushort*)w;          w += (size_t)N * 64 * 2;
  uint2* tmp_r = (uint2*)w;          w += (size_t)E * 8;
  uint2* tmp_s = (uint2*)w;          w += (size_t)E * 8;
  uint2* srt_r = (uint2*)w;          w += (size_t)E * 8;
  uint2* srt_s = (uint2*)w;          w += (size_t)E * 8;
  uint* cnt_r = (uint*)w;            w += (size_t)N * 4;
  uint* cnt_s = (uint*)w;            w += (size_t)N * 4;
  ushort* xb = (ushort*)w;           w += (size_t)N * 16 * 2;
  ushort* wt_lin = (ushort*)w;       w += (size_t)64 * 64 * 2;
  ushort* wnb_img = (ushort*)w;      w += (size_t)64 * 128 * 2;
  ushort* wtd1_img = (ushort*)w;     w += (size_t)64 * 192 * 2;
  ushort* w2_img = (ushort*)w;       w += (size_t)16 * 64 * 2;
  uint* start_r = (uint*)w;          w += (size_t)(NB + 1) * 4;
  uint* start_s = (uint*)w;          w += (size_t)(NB + 1) * 4;
  uint* cur_r = (uint*)w;            w += (size_t)NB * 4;
  uint* cur_s = (uint*)w;            w += (size_t)NB * 4;
  // zeroed region
  uint* bcnt_r = (uint*)w;           w += (size_t)NBMAX * 4;
  uint* bcnt_s = (uint*)w;           w += (size_t)NBMAX * 4;
  float* e_sum = (float*)w;          w += 64 * 4;
  float* n_sum = (float*)w;          w += 64 * 4;
  // small non-zeroed
  float* eb_init = (float*)w;        w += 64 * 4;
  float* nb_init = (float*)w;        w += 64 * 4;

  size_t zero_bytes = (size_t)(2 * NBMAX + 128) * 4;
  hipMemsetAsync(bcnt_r, 0, zero_bytes, stream);
  hipMemsetAsync(sum_recv, 0, (size_t)N * 128 * 4, stream);

  hipLaunchKernelGGL(init_kernel, dim3(1 + nxb + 64), dim3(256), 0, stream, x,
                     xb, N * 16, nxb, receivers, senders, bcnt_r, bcnt_s, E,
                     NB, u, W_eb, b_eb, W_nb, b_nb, W_d1, W_d2, eb_init,
                     nb_init, wt_lin, wnb_img, wtd1_img, w2_img);
  hipLaunchKernelGGL(bscan_kernel, dim3(1), dim3(256), 0, stream, bcnt_r,
                     bcnt_s, start_r, start_s, cur_r, cur_s, E, NB);
  hipLaunchKernelGGL(distribute_kernel, dim3(2 * NDB), dim3(256), 0, stream,
                     receivers, senders, cur_r, cur_s, tmp_r, tmp_s, E, NB);
  hipLaunchKernelGGL(bucketsort_kernel, dim3(2 * NB), dim3(256), 0, stream,
                     tmp_r, tmp_s, start_r, start_s, srt_r, srt_s, cnt_r,
                     cnt_s, N);
  hipLaunchKernelGGL(escatter_kernel, dim3(4096), dim3(256), 0, stream,
                     edge_attr, xb, srt_r, srt_s, wt_lin, eb_init, sum_recv,
                     sum_sent, E, ntiles);
  hipLaunchKernelGGL(node_mfma_kernel, dim3((N + 63) / 64), dim3(256), 0,
                     stream, sum_recv, xb, wnb_img, nb_init, n_h, e_sum,
                     n_sum, N);
  hipLaunchKernelGGL(decoder_mfma_kernel, dim3((N + 63) / 64), dim3(256), 0,
                     stream, sum_recv, sum_sent, cnt_r, cnt_s, n_h, wtd1_img,
                     w2_img, b_d2, u, e_sum, n_sum, W_gb, b_gb, W_d1, b_d1,
                     (float*)d_out, 1.0f / (float)E, 1.0f / (float)N, N);
}